// Round 4
// baseline (536.090 us; speedup 1.0000x reference)
//
#include <hip/hip_runtime.h>
#include <math.h>

#define B_N 1024
#define D_K 512
#define C_N 100000
#define SCALEF 30.0f
#define COS_M 0.9553364891256061f
#define SIN_M 0.29552020666133955f
#define TH_C (-0.9553364891256061f)
#define MM_C 0.08865606199840186f
#define FIXM 160.0f

#define BM 128
#define BN 128
#define BK 64
#define NCT ((C_N + BN - 1) / BN)   // 782
#define NCTP 784                    // padded to multiple of 8 for XCD swizzle

typedef short bf16x8 __attribute__((ext_vector_type(8)));
typedef float f32x4  __attribute__((ext_vector_type(4)));

__device__ inline unsigned bf16rne(float f) {
    unsigned u = __float_as_uint(f);
    u += 0x7fffu + ((u >> 16) & 1u);
    return u >> 16;
}
__device__ inline unsigned pk2(float lo, float hi) {
    return bf16rne(lo) | (bf16rne(hi) << 16);
}

__device__ static __forceinline__ void async16(const void* g, void* l) {
    __builtin_amdgcn_global_load_lds(
        (const __attribute__((address_space(1))) unsigned int*)g,
        (__attribute__((address_space(3))) unsigned int*)l, 16, 0, 0);
}

// ---------- kernel W: fused row-norm + f32->bf16 convert of weight ----------
__global__ __launch_bounds__(256) void wcvt_kernel(const float* __restrict__ w,
                                                   unsigned short* __restrict__ wbf) {
    int wave = threadIdx.x >> 6;
    int lane = threadIdx.x & 63;
    int c = blockIdx.x * 4 + wave;
    if (c >= C_N) return;
    const float4* p = (const float4*)(w + (size_t)c * D_K);
    float4 a = p[lane];
    float4 b = p[lane + 64];
    float s = a.x*a.x + a.y*a.y + a.z*a.z + a.w*a.w
            + b.x*b.x + b.y*b.y + b.z*b.z + b.w*b.w;
    #pragma unroll
    for (int off = 32; off; off >>= 1) s += __shfl_xor(s, off, 64);
    float rn = 1.0f / sqrtf(s);
    uint2 o0, o1;
    o0.x = pk2(a.x * rn, a.y * rn); o0.y = pk2(a.z * rn, a.w * rn);
    o1.x = pk2(b.x * rn, b.y * rn); o1.y = pk2(b.z * rn, b.w * rn);
    uint2* q = (uint2*)(wbf + (size_t)c * D_K);
    q[lane] = o0;
    q[lane + 64] = o1;
}

// ---------------- kernel A2: embeddings f32 -> bf16 ----------------
__global__ __launch_bounds__(256) void embcvt_kernel(const float* __restrict__ e,
                                                     unsigned short* __restrict__ ebf) {
    int i = blockIdx.x * 256 + threadIdx.x;
    float4 v = ((const float4*)e)[i];
    uint2 o;
    o.x = pk2(v.x, v.y);
    o.y = pk2(v.z, v.w);
    ((uint2*)ebf)[i] = o;
}

// ------------- kernel B: MFMA GEMM, BK=64, swizzled LDS, conflict-free -------------
// LDS layout: row r (0..127), 8 chunks of 16 B per row; global k-chunk cl of row r
// stored at slot (cl + r) & 7  -> fragment b128 reads hit all 8 bank-quads evenly.
__global__ __launch_bounds__(256) void gemm_lse_kernel(
    const unsigned short* __restrict__ ebf, const unsigned short* __restrict__ wbf,
    const int* __restrict__ labels,
    float* __restrict__ partial, float* __restrict__ target)
{
    __shared__ short As[BM * BK];   // 16 KB
    __shared__ short Bs[BN * BK];   // 16 KB
    __shared__ int   labS[BM];
    __shared__ float sS[BM][2];

    // XCD swizzle: bid = 64g + 8r + j -> ct = 8g+j (same XCD covers all 8 r of a ct)
    const int bid = blockIdx.x;
    const int g8 = bid >> 6, r8 = (bid >> 3) & 7, j8 = bid & 7;
    const int ct = g8 * 8 + j8;     // 0..783 (782,783 dummy)
    const int rt = r8;
    const int row0 = rt * BM;
    const int col0 = ct * BN;
    const int t = threadIdx.x;
    const int lane = t & 63, wave = t >> 6;
    const int wx = wave & 1, wy = wave >> 1;
    const int lc = lane & 15, q = lane >> 4;

    if (t < BM) labS[t] = labels[row0 + t];
    __syncthreads();

    // staging: thread t stages rows r_p = 32p + (t>>3), p=0..3, slot s = t&7.
    // global chunk for slot s of row r: gch = (s - r) & 7  (constant across p: 32p%8==0)
    const int srow = t >> 3;
    const int sslot = t & 7;
    const int gch = (sslot - srow) & 7;
    const unsigned short* aptr = ebf + (size_t)(row0 + srow) * D_K + gch * 8;
    int bR[4];
    #pragma unroll
    for (int p = 0; p < 4; ++p) {
        int br = col0 + 32 * p + srow;
        bR[p] = (br < C_N) ? br : (C_N - 1);
    }
    const unsigned short* bptr[4] = {
        wbf + (size_t)bR[0] * D_K + gch * 8, wbf + (size_t)bR[1] * D_K + gch * 8,
        wbf + (size_t)bR[2] * D_K + gch * 8, wbf + (size_t)bR[3] * D_K + gch * 8 };
    short* ldsA = As + t * 8;       // + p*2048 shorts (4 KB)
    short* ldsB = Bs + t * 8;

    f32x4 acc[4][4] = {};

    for (int it = 0; it < D_K / BK; ++it) {
        const int k0 = it * BK;
        __syncthreads();   // previous iter's fragment reads complete
        #pragma unroll
        for (int p = 0; p < 4; ++p)
            async16(aptr + (size_t)32 * p * D_K + k0, ldsA + p * 2048);
        #pragma unroll
        for (int p = 0; p < 4; ++p)
            async16(bptr[p] + k0, ldsB + p * 2048);
        __syncthreads();   // drains vmcnt -> tiles ready

        #pragma unroll
        for (int kh = 0; kh < 2; ++kh) {
            bf16x8 aF[4], bF[4];
            #pragma unroll
            for (int si = 0; si < 4; ++si) {
                int r = wy * 64 + si * 16 + lc;
                int slot = (kh * 4 + q + r) & 7;
                aF[si] = *(const bf16x8*)(As + r * BK + slot * 8);
            }
            #pragma unroll
            for (int sj = 0; sj < 4; ++sj) {
                int r = wx * 64 + sj * 16 + lc;
                int slot = (kh * 4 + q + r) & 7;
                bF[sj] = *(const bf16x8*)(Bs + r * BK + slot * 8);
            }
            #pragma unroll
            for (int si = 0; si < 4; ++si)
                #pragma unroll
                for (int sj = 0; sj < 4; ++sj)
                    acc[si][sj] = __builtin_amdgcn_mfma_f32_16x16x32_bf16(
                        aF[si], bF[sj], acc[si][sj], 0, 0, 0);
        }
    }

    // ---- epilogue: fixed-max exp-sum over this wave's 64 cols ----
    // C/D layout: col = lane&15, row = quad*4 + reg
    #pragma unroll
    for (int si = 0; si < 4; ++si) {
        #pragma unroll
        for (int reg = 0; reg < 4; ++reg) {
            int rl = wy * 64 + si * 16 + q * 4 + reg;
            int lab = labS[rl];
            float s = 0.0f;
            #pragma unroll
            for (int sj = 0; sj < 4; ++sj) {
                int cg = col0 + wx * 64 + sj * 16 + lc;
                float cosv = acc[si][sj][reg];
                float v;
                if (cg == lab) {
                    float sine = sqrtf(fminf(fmaxf(1.0f - cosv * cosv, 0.0f), 1.0f));
                    float phi = cosv * COS_M - sine * SIN_M;
                    phi = (cosv > TH_C) ? phi : (cosv - MM_C);
                    v = SCALEF * phi;
                    target[row0 + rl] = v;
                } else {
                    v = SCALEF * cosv;
                }
                if (cg < C_N) s += __expf(v - FIXM);
            }
            #pragma unroll
            for (int off = 1; off < 16; off <<= 1)
                s += __shfl_xor(s, off, 64);
            if (lc == 0) sS[rl][wx] = s;
        }
    }
    __syncthreads();
    if (t < BM && ct < NCT)
        partial[(size_t)ct * B_N + row0 + t] = sS[t][0] + sS[t][1];   // [ct][b], coalesced
}

// ------------- kernel C1: sum partials per row -> nll[b] -------------
__global__ __launch_bounds__(256) void lse_reduce_kernel(
    const float* __restrict__ partial, const float* __restrict__ target,
    float* __restrict__ nll)
{
    __shared__ float sS[2][128];
    int b0 = blockIdx.x * 128;
    int tb = threadIdx.x & 127;
    int tc = threadIdx.x >> 7;
    float s = 0.0f;
    for (int ct = tc; ct < NCT; ct += 2)
        s += partial[(size_t)ct * B_N + b0 + tb];
    sS[tc][tb] = s;
    __syncthreads();
    if (threadIdx.x < 128) {
        float tot = sS[0][tb] + sS[1][tb];
        nll[b0 + tb] = (FIXM + logf(tot)) - target[b0 + tb];
    }
}

// ------------- kernel C2: mean over batch -------------
__global__ __launch_bounds__(1024) void mean_kernel(const float* __restrict__ nll,
                                                    float* __restrict__ out) {
    int t = threadIdx.x;
    float v = nll[t];
    #pragma unroll
    for (int off = 1; off < 64; off <<= 1) v += __shfl_xor(v, off, 64);
    __shared__ float ws[16];
    int wave = t >> 6, lane = t & 63;
    if (lane == 0) ws[wave] = v;
    __syncthreads();
    if (t == 0) {
        float sum = 0.f;
        for (int w = 0; w < 16; ++w) sum += ws[w];
        out[0] = sum / (float)B_N;
    }
}

// ===================== fallback path (round-2 structure, small ws) =====================
__global__ __launch_bounds__(256) void rnorm_fb_kernel(const float* __restrict__ w,
                                                       float* __restrict__ rnorm) {
    int wave = threadIdx.x >> 6;
    int lane = threadIdx.x & 63;
    int c = blockIdx.x * 4 + wave;
    if (c >= C_N) return;
    const float4* p = (const float4*)(w + (size_t)c * D_K);
    float4 a = p[lane];
    float4 b = p[lane + 64];
    float s = a.x*a.x + a.y*a.y + a.z*a.z + a.w*a.w
            + b.x*b.x + b.y*b.y + b.z*b.z + b.w*b.w;
    #pragma unroll
    for (int off = 32; off; off >>= 1) s += __shfl_xor(s, off, 64);
    if (lane == 0) rnorm[c] = 1.0f / sqrtf(s);
}

__device__ inline void merge_ms(float& m, float& s, float m2, float s2) {
    float M = fmaxf(m, m2);
    if (M != -INFINITY) {
        s = s * __expf(m - M) + s2 * __expf(m2 - M);
        m = M;
    }
}

#define ROWS 40
__global__ __launch_bounds__(256) void gemm_lse_fb_kernel(
    const unsigned short* __restrict__ ebf, const float* __restrict__ wgt,
    const int* __restrict__ labels, const float* __restrict__ rnorm,
    float2* __restrict__ partial, float* __restrict__ target)
{
    __shared__ short As[BM * ROWS];
    __shared__ short Bs[BN * ROWS];
    __shared__ float rnS[BN];
    __shared__ int   labS[BM];
    __shared__ float2 msS[BM][2];

    const int rt = blockIdx.x;
    const int ct = blockIdx.y;
    const int row0 = rt * BM;
    const int col0 = ct * BN;
    const int t = threadIdx.x;
    const int lane = t & 63, wave = t >> 6;
    const int wx = wave & 1, wy = wave >> 1;
    const int lc = lane & 15, q = lane >> 4;

    if (t < BN) {
        int c = col0 + t;
        rnS[t] = (c < C_N) ? rnorm[c] : 0.0f;
    } else {
        labS[t - BN] = labels[row0 + (t - BN)];
    }
    __syncthreads();

    const int sr = t >> 1;
    const int sh = t & 1;
    const int cB = col0 + sr;
    const bool bval = cB < C_N;
    const float rn = rnS[sr];
    const unsigned short* aptr = ebf + (size_t)(row0 + sr) * D_K + sh * 16;
    const float* bptr0 = wgt + (size_t)(bval ? cB : 0) * D_K + sh * 16;

    f32x4 acc[4][4] = {};

    for (int it = 0; it < D_K / 32; ++it) {
        const int k0 = it * 32;
        uint4 a0 = ((const uint4*)(aptr + k0))[0];
        uint4 a1 = ((const uint4*)(aptr + k0))[1];
        float4 b0 = make_float4(0.f,0.f,0.f,0.f), b1 = b0, b2 = b0, b3 = b0;
        if (bval) {
            const float4* bp = (const float4*)(bptr0 + k0);
            b0 = bp[0]; b1 = bp[1]; b2 = bp[2]; b3 = bp[3];
        }
        uint4 w0, w1;
        w0.x = pk2(b0.x * rn, b0.y * rn); w0.y = pk2(b0.z * rn, b0.w * rn);
        w0.z = pk2(b1.x * rn, b1.y * rn); w0.w = pk2(b1.z * rn, b1.w * rn);
        w1.x = pk2(b2.x * rn, b2.y * rn); w1.y = pk2(b2.z * rn, b2.w * rn);
        w1.z = pk2(b3.x * rn, b3.y * rn); w1.w = pk2(b3.z * rn, b3.w * rn);

        __syncthreads();
        *(uint4*)(As + sr * ROWS + sh * 16)     = a0;
        *(uint4*)(As + sr * ROWS + sh * 16 + 8) = a1;
        *(uint4*)(Bs + sr * ROWS + sh * 16)     = w0;
        *(uint4*)(Bs + sr * ROWS + sh * 16 + 8) = w1;
        __syncthreads();

        bf16x8 aF[4], bF[4];
        #pragma unroll
        for (int si = 0; si < 4; ++si)
            aF[si] = *(const bf16x8*)(As + (wy * 64 + si * 16 + lc) * ROWS + q * 8);
        #pragma unroll
        for (int sj = 0; sj < 4; ++sj)
            bF[sj] = *(const bf16x8*)(Bs + (wx * 64 + sj * 16 + lc) * ROWS + q * 8);
        #pragma unroll
        for (int si = 0; si < 4; ++si)
            #pragma unroll
            for (int sj = 0; sj < 4; ++sj)
                acc[si][sj] = __builtin_amdgcn_mfma_f32_16x16x32_bf16(
                    aF[si], bF[sj], acc[si][sj], 0, 0, 0);
    }

    #pragma unroll
    for (int si = 0; si < 4; ++si) {
        #pragma unroll
        for (int reg = 0; reg < 4; ++reg) {
            int rl = wy * 64 + si * 16 + q * 4 + reg;
            int lab = labS[rl];
            float lg[4];
            float mx = -INFINITY;
            #pragma unroll
            for (int sj = 0; sj < 4; ++sj) {
                int cg = col0 + wx * 64 + sj * 16 + lc;
                float cosv = acc[si][sj][reg];
                float v;
                if (cg == lab) {
                    float sine = sqrtf(fminf(fmaxf(1.0f - cosv * cosv, 0.0f), 1.0f));
                    float phi = cosv * COS_M - sine * SIN_M;
                    phi = (cosv > TH_C) ? phi : (cosv - MM_C);
                    v = SCALEF * phi;
                    target[row0 + rl] = v;
                } else {
                    v = SCALEF * cosv;
                }
                if (cg >= C_N) v = -INFINITY;
                lg[sj] = v;
                mx = fmaxf(mx, v);
            }
            #pragma unroll
            for (int off = 1; off < 16; off <<= 1)
                mx = fmaxf(mx, __shfl_xor(mx, off, 64));
            float s = 0.0f;
            #pragma unroll
            for (int sj = 0; sj < 4; ++sj)
                if (lg[sj] != -INFINITY) s += __expf(lg[sj] - mx);
            #pragma unroll
            for (int off = 1; off < 16; off <<= 1)
                s += __shfl_xor(s, off, 64);
            if (lc == 0) msS[rl][wx] = make_float2(mx, s);
        }
    }
    __syncthreads();
    if (t < BM) {
        float2 p0 = msS[t][0], p1 = msS[t][1];
        float m = p0.x, s = p0.y;
        float M = fmaxf(m, p1.x);
        if (M != -INFINITY) {
            s = s * __expf(m - M) + p1.y * __expf(p1.x - M);
            m = M;
        }
        partial[(size_t)(row0 + t) * NCT + ct] = make_float2(m, s);
    }
}

__global__ __launch_bounds__(256) void lse_reduce_fb_kernel(
    const float2* __restrict__ partial, const float* __restrict__ target,
    float* __restrict__ nll)
{
    int b = blockIdx.x;
    int t = threadIdx.x;
    float m = -INFINITY, s = 0.0f;
    for (int ct = t; ct < NCT; ct += 256) {
        float2 p = partial[(size_t)b * NCT + ct];
        merge_ms(m, s, p.x, p.y);
    }
    #pragma unroll
    for (int off = 1; off < 64; off <<= 1) {
        float m2 = __shfl_xor(m, off, 64);
        float s2 = __shfl_xor(s, off, 64);
        merge_ms(m, s, m2, s2);
    }
    __shared__ float ms[4], ss[4];
    int wave = t >> 6, lane = t & 63;
    if (lane == 0) { ms[wave] = m; ss[wave] = s; }
    __syncthreads();
    if (t == 0) {
        m = ms[0]; s = ss[0];
        for (int w = 1; w < 4; ++w) merge_ms(m, s, ms[w], ss[w]);
        nll[b] = (m + logf(s)) - target[b];
    }
}

extern "C" void kernel_launch(void* const* d_in, const int* in_sizes, int n_in,
                              void* d_out, int out_size, void* d_ws, size_t ws_size,
                              hipStream_t stream) {
    const float* emb    = (const float*)d_in[0];
    const int*   labels = (const int*)d_in[1];
    const float* wgt    = (const float*)d_in[2];
    float* out = (float*)d_out;
    char* ws = (char*)d_ws;

    if (ws_size >= 106659840ull) {
        // ---- fast path: bf16 weight copy in workspace ----
        float* target        = (float*)(ws);                    // 4096
        float* nll           = (float*)(ws + 4096);             // 4096
        float* partial       = (float*)(ws + 8192);             // 782*1024*4 = 3203072
        unsigned short* ebf  = (unsigned short*)(ws + 3211264); // 1048576
        unsigned short* wbf  = (unsigned short*)(ws + 4259840); // 102400000

        wcvt_kernel<<<C_N / 4, 256, 0, stream>>>(wgt, wbf);
        embcvt_kernel<<<(B_N * D_K / 4) / 256, 256, 0, stream>>>(emb, ebf);
        gemm_lse_kernel<<<(NCTP / 8) * 64, 256, 0, stream>>>(ebf, wbf, labels, partial, target);
        lse_reduce_kernel<<<B_N / 128, 256, 0, stream>>>(partial, target, nll);
        mean_kernel<<<1, 1024, 0, stream>>>(nll, out);
    } else {
        // ---- fallback: round-2 structure ----
        float*  rnorm   = (float*)(ws);                        // 400000
        float*  target  = (float*)(ws + 400000);               // 4096
        float*  nll     = (float*)(ws + 404096);               // 4096
        float2* partial = (float2*)(ws + 408192);              // 6406144
        unsigned short* ebf = (unsigned short*)(ws + 6814336); // 1048576

        rnorm_fb_kernel<<<C_N / 4, 256, 0, stream>>>(wgt, rnorm);
        embcvt_kernel<<<(B_N * D_K / 4) / 256, 256, 0, stream>>>(emb, ebf);
        dim3 gridB(B_N / BM, NCT);
        gemm_lse_fb_kernel<<<gridB, 256, 0, stream>>>(ebf, wgt, labels, rnorm, partial, target);
        lse_reduce_fb_kernel<<<B_N, 256, 0, stream>>>(partial, target, nll);
        mean_kernel<<<1, 1024, 0, stream>>>(nll, out);
    }
}

// Round 5
// 489.310 us; speedup vs baseline: 1.0956x; 1.0956x over previous
//
#include <hip/hip_runtime.h>
#include <math.h>

#define B_N 1024
#define D_K 512
#define C_N 100000
#define SCALEF 30.0f
#define COS_M 0.9553364891256061f
#define SIN_M 0.29552020666133955f
#define TH_C (-0.9553364891256061f)
#define MM_C 0.08865606199840186f
#define FIXM 160.0f

#define BM 128
#define BN 128
#define BK 64
#define NCT ((C_N + BN - 1) / BN)   // 782
#define NCTP 784                    // padded to multiple of 8 for XCD swizzle

typedef short bf16x8 __attribute__((ext_vector_type(8)));
typedef float f32x4  __attribute__((ext_vector_type(4)));

__device__ inline unsigned bf16rne(float f) {
    unsigned u = __float_as_uint(f);
    u += 0x7fffu + ((u >> 16) & 1u);
    return u >> 16;
}
__device__ inline unsigned pk2(float lo, float hi) {
    return bf16rne(lo) | (bf16rne(hi) << 16);
}

__device__ static __forceinline__ void async16(const void* g, void* l) {
    __builtin_amdgcn_global_load_lds(
        (const __attribute__((address_space(1))) unsigned int*)g,
        (__attribute__((address_space(3))) unsigned int*)l, 16, 0, 0);
}

// ---------- kernel P: fused weight-norm-convert + emb-convert + acc-zero ----------
// blocks [0,25000): normalize+convert 4 W rows each
// blocks [25000,25512): convert embeddings
// block 25512: zero gacc[1024]
__global__ __launch_bounds__(256) void prep_kernel(
    const float* __restrict__ w, unsigned short* __restrict__ wbf,
    const float* __restrict__ e, unsigned short* __restrict__ ebf,
    float* __restrict__ gacc)
{
    int bid = blockIdx.x;
    if (bid < 25000) {
        int wave = threadIdx.x >> 6;
        int lane = threadIdx.x & 63;
        int c = bid * 4 + wave;
        const float4* p = (const float4*)(w + (size_t)c * D_K);
        float4 a = p[lane];
        float4 b = p[lane + 64];
        float s = a.x*a.x + a.y*a.y + a.z*a.z + a.w*a.w
                + b.x*b.x + b.y*b.y + b.z*b.z + b.w*b.w;
        #pragma unroll
        for (int off = 32; off; off >>= 1) s += __shfl_xor(s, off, 64);
        float rn = 1.0f / sqrtf(s);
        uint2 o0, o1;
        o0.x = pk2(a.x * rn, a.y * rn); o0.y = pk2(a.z * rn, a.w * rn);
        o1.x = pk2(b.x * rn, b.y * rn); o1.y = pk2(b.z * rn, b.w * rn);
        uint2* q = (uint2*)(wbf + (size_t)c * D_K);
        q[lane] = o0;
        q[lane + 64] = o1;
    } else if (bid < 25512) {
        int i = (bid - 25000) * 256 + threadIdx.x;
        float4 v = ((const float4*)e)[i];
        uint2 o;
        o.x = pk2(v.x, v.y);
        o.y = pk2(v.z, v.w);
        ((uint2*)ebf)[i] = o;
    } else {
        float4 z = make_float4(0.f, 0.f, 0.f, 0.f);
        ((float4*)gacc)[threadIdx.x] = z;   // 256 * 16 B = 4 KB
    }
}

// ------------- kernel B: MFMA GEMM, BK=64, swizzled LDS, atomic row-sums -------------
// LDS layout: row r (0..127), 8 chunks of 16 B per row; global k-chunk cl of row r
// stored at slot (cl + r) & 7  -> fragment b128 reads hit all 8 bank-quads evenly.
__global__ __launch_bounds__(256) void gemm_lse_kernel(
    const unsigned short* __restrict__ ebf, const unsigned short* __restrict__ wbf,
    const int* __restrict__ labels,
    float* __restrict__ gacc, float* __restrict__ target)
{
    __shared__ short As[BM * BK];   // 16 KB
    __shared__ short Bs[BN * BK];   // 16 KB
    __shared__ int   labS[BM];

    // XCD swizzle: bid = 64g + 8r + j -> ct = 8g+j (same XCD covers all 8 r of a ct)
    const int bid = blockIdx.x;
    const int g8 = bid >> 6, r8 = (bid >> 3) & 7, j8 = bid & 7;
    const int ct = g8 * 8 + j8;     // 0..783 (782,783 dummy: contribute s=0)
    const int rt = r8;
    const int row0 = rt * BM;
    const int col0 = ct * BN;
    const int t = threadIdx.x;
    const int lane = t & 63, wave = t >> 6;
    const int wx = wave & 1, wy = wave >> 1;
    const int lc = lane & 15, q = lane >> 4;

    if (t < BM) labS[t] = labels[row0 + t];
    __syncthreads();

    // staging: thread t stages rows r_p = 32p + (t>>3), p=0..3, slot s = t&7.
    // global chunk for slot s of row r: gch = (s - r) & 7  (constant across p)
    const int srow = t >> 3;
    const int sslot = t & 7;
    const int gch = (sslot - srow) & 7;
    const unsigned short* aptr = ebf + (size_t)(row0 + srow) * D_K + gch * 8;
    int bR[4];
    #pragma unroll
    for (int p = 0; p < 4; ++p) {
        int br = col0 + 32 * p + srow;
        bR[p] = (br < C_N) ? br : (C_N - 1);
    }
    const unsigned short* bptr[4] = {
        wbf + (size_t)bR[0] * D_K + gch * 8, wbf + (size_t)bR[1] * D_K + gch * 8,
        wbf + (size_t)bR[2] * D_K + gch * 8, wbf + (size_t)bR[3] * D_K + gch * 8 };
    short* ldsA = As + t * 8;       // + p*2048 shorts (4 KB)
    short* ldsB = Bs + t * 8;

    f32x4 acc[4][4] = {};

    for (int it = 0; it < D_K / BK; ++it) {
        const int k0 = it * BK;
        __syncthreads();   // previous iter's fragment reads complete
        #pragma unroll
        for (int p = 0; p < 4; ++p)
            async16(aptr + (size_t)32 * p * D_K + k0, ldsA + p * 2048);
        #pragma unroll
        for (int p = 0; p < 4; ++p)
            async16(bptr[p] + k0, ldsB + p * 2048);
        __syncthreads();   // drains vmcnt -> tiles ready

        #pragma unroll
        for (int kh = 0; kh < 2; ++kh) {
            bf16x8 aF[4], bF[4];
            #pragma unroll
            for (int si = 0; si < 4; ++si) {
                int r = wy * 64 + si * 16 + lc;
                int slot = (kh * 4 + q + r) & 7;
                aF[si] = *(const bf16x8*)(As + r * BK + slot * 8);
            }
            #pragma unroll
            for (int sj = 0; sj < 4; ++sj) {
                int r = wx * 64 + sj * 16 + lc;
                int slot = (kh * 4 + q + r) & 7;
                bF[sj] = *(const bf16x8*)(Bs + r * BK + slot * 8);
            }
            #pragma unroll
            for (int si = 0; si < 4; ++si)
                #pragma unroll
                for (int sj = 0; sj < 4; ++sj)
                    acc[si][sj] = __builtin_amdgcn_mfma_f32_16x16x32_bf16(
                        aF[si], bF[sj], acc[si][sj], 0, 0, 0);
        }
    }

    // ---- epilogue: fixed-max exp-sum over this wave's 64 cols, atomic per row ----
    // C/D layout: col = lane&15, row = quad*4 + reg
    #pragma unroll
    for (int si = 0; si < 4; ++si) {
        #pragma unroll
        for (int reg = 0; reg < 4; ++reg) {
            int rl = wy * 64 + si * 16 + q * 4 + reg;
            int lab = labS[rl];
            float s = 0.0f;
            #pragma unroll
            for (int sj = 0; sj < 4; ++sj) {
                int cg = col0 + wx * 64 + sj * 16 + lc;
                float cosv = acc[si][sj][reg];
                float v;
                if (cg == lab) {
                    float sine = sqrtf(fminf(fmaxf(1.0f - cosv * cosv, 0.0f), 1.0f));
                    float phi = cosv * COS_M - sine * SIN_M;
                    phi = (cosv > TH_C) ? phi : (cosv - MM_C);
                    v = SCALEF * phi;
                    target[row0 + rl] = v;
                } else {
                    v = SCALEF * cosv;
                }
                if (cg < C_N) s += __expf(v - FIXM);
            }
            #pragma unroll
            for (int off = 1; off < 16; off <<= 1)
                s += __shfl_xor(s, off, 64);
            if (lc == 0) atomicAdd(&gacc[row0 + rl], s);
        }
    }
}

// ------------- kernel F: nll + mean in one block -------------
__global__ __launch_bounds__(1024) void finish_kernel(
    const float* __restrict__ gacc, const float* __restrict__ target,
    float* __restrict__ out)
{
    int t = threadIdx.x;
    float v = (FIXM + logf(gacc[t])) - target[t];
    #pragma unroll
    for (int off = 1; off < 64; off <<= 1) v += __shfl_xor(v, off, 64);
    __shared__ float ws[16];
    int wave = t >> 6, lane = t & 63;
    if (lane == 0) ws[wave] = v;
    __syncthreads();
    if (t == 0) {
        float sum = 0.f;
        for (int w = 0; w < 16; ++w) sum += ws[w];
        out[0] = sum / (float)B_N;
    }
}

// ===================== fallback path (small ws: on-the-fly W convert) =====================
__global__ __launch_bounds__(256) void prep_fb_kernel(
    const float* __restrict__ w, float* __restrict__ rnorm,
    const float* __restrict__ e, unsigned short* __restrict__ ebf,
    float* __restrict__ gacc)
{
    int bid = blockIdx.x;
    if (bid < 25000) {
        int wave = threadIdx.x >> 6;
        int lane = threadIdx.x & 63;
        int c = bid * 4 + wave;
        const float4* p = (const float4*)(w + (size_t)c * D_K);
        float4 a = p[lane];
        float4 b = p[lane + 64];
        float s = a.x*a.x + a.y*a.y + a.z*a.z + a.w*a.w
                + b.x*b.x + b.y*b.y + b.z*b.z + b.w*b.w;
        #pragma unroll
        for (int off = 32; off; off >>= 1) s += __shfl_xor(s, off, 64);
        if (lane == 0) rnorm[c] = 1.0f / sqrtf(s);
    } else if (bid < 25512) {
        int i = (bid - 25000) * 256 + threadIdx.x;
        float4 v = ((const float4*)e)[i];
        uint2 o;
        o.x = pk2(v.x, v.y);
        o.y = pk2(v.z, v.w);
        ((uint2*)ebf)[i] = o;
    } else {
        float4 z = make_float4(0.f, 0.f, 0.f, 0.f);
        ((float4*)gacc)[threadIdx.x] = z;
    }
}

#define ROWS 40
__global__ __launch_bounds__(256) void gemm_lse_fb_kernel(
    const unsigned short* __restrict__ ebf, const float* __restrict__ wgt,
    const int* __restrict__ labels, const float* __restrict__ rnorm,
    float* __restrict__ gacc, float* __restrict__ target)
{
    __shared__ short As[BM * ROWS];
    __shared__ short Bs[BN * ROWS];
    __shared__ float rnS[BN];
    __shared__ int   labS[BM];

    const int rt = blockIdx.x;
    const int ct = blockIdx.y;
    const int row0 = rt * BM;
    const int col0 = ct * BN;
    const int t = threadIdx.x;
    const int lane = t & 63, wave = t >> 6;
    const int wx = wave & 1, wy = wave >> 1;
    const int lc = lane & 15, q = lane >> 4;

    if (t < BN) {
        int c = col0 + t;
        rnS[t] = (c < C_N) ? rnorm[c] : 0.0f;
    } else {
        labS[t - BN] = labels[row0 + (t - BN)];
    }
    __syncthreads();

    const int sr = t >> 1;
    const int sh = t & 1;
    const int cB = col0 + sr;
    const bool bval = cB < C_N;
    const float rn = rnS[sr];
    const unsigned short* aptr = ebf + (size_t)(row0 + sr) * D_K + sh * 16;
    const float* bptr0 = wgt + (size_t)(bval ? cB : 0) * D_K + sh * 16;

    f32x4 acc[4][4] = {};

    for (int it = 0; it < D_K / 32; ++it) {
        const int k0 = it * 32;
        uint4 a0 = ((const uint4*)(aptr + k0))[0];
        uint4 a1 = ((const uint4*)(aptr + k0))[1];
        float4 b0 = make_float4(0.f,0.f,0.f,0.f), b1 = b0, b2 = b0, b3 = b0;
        if (bval) {
            const float4* bp = (const float4*)(bptr0 + k0);
            b0 = bp[0]; b1 = bp[1]; b2 = bp[2]; b3 = bp[3];
        }
        uint4 w0, w1;
        w0.x = pk2(b0.x * rn, b0.y * rn); w0.y = pk2(b0.z * rn, b0.w * rn);
        w0.z = pk2(b1.x * rn, b1.y * rn); w0.w = pk2(b1.z * rn, b1.w * rn);
        w1.x = pk2(b2.x * rn, b2.y * rn); w1.y = pk2(b2.z * rn, b2.w * rn);
        w1.z = pk2(b3.x * rn, b3.y * rn); w1.w = pk2(b3.z * rn, b3.w * rn);

        __syncthreads();
        *(uint4*)(As + sr * ROWS + sh * 16)     = a0;
        *(uint4*)(As + sr * ROWS + sh * 16 + 8) = a1;
        *(uint4*)(Bs + sr * ROWS + sh * 16)     = w0;
        *(uint4*)(Bs + sr * ROWS + sh * 16 + 8) = w1;
        __syncthreads();

        bf16x8 aF[4], bF[4];
        #pragma unroll
        for (int si = 0; si < 4; ++si)
            aF[si] = *(const bf16x8*)(As + (wy * 64 + si * 16 + lc) * ROWS + q * 8);
        #pragma unroll
        for (int sj = 0; sj < 4; ++sj)
            bF[sj] = *(const bf16x8*)(Bs + (wx * 64 + sj * 16 + lc) * ROWS + q * 8);
        #pragma unroll
        for (int si = 0; si < 4; ++si)
            #pragma unroll
            for (int sj = 0; sj < 4; ++sj)
                acc[si][sj] = __builtin_amdgcn_mfma_f32_16x16x32_bf16(
                    aF[si], bF[sj], acc[si][sj], 0, 0, 0);
    }

    #pragma unroll
    for (int si = 0; si < 4; ++si) {
        #pragma unroll
        for (int reg = 0; reg < 4; ++reg) {
            int rl = wy * 64 + si * 16 + q * 4 + reg;
            int lab = labS[rl];
            float s = 0.0f;
            #pragma unroll
            for (int sj = 0; sj < 4; ++sj) {
                int cg = col0 + wx * 64 + sj * 16 + lc;
                float cosv = acc[si][sj][reg];
                float v;
                if (cg == lab) {
                    float sine = sqrtf(fminf(fmaxf(1.0f - cosv * cosv, 0.0f), 1.0f));
                    float phi = cosv * COS_M - sine * SIN_M;
                    phi = (cosv > TH_C) ? phi : (cosv - MM_C);
                    v = SCALEF * phi;
                    target[row0 + rl] = v;
                } else {
                    v = SCALEF * cosv;
                }
                if (cg < C_N) s += __expf(v - FIXM);
            }
            #pragma unroll
            for (int off = 1; off < 16; off <<= 1)
                s += __shfl_xor(s, off, 64);
            if (lc == 0) atomicAdd(&gacc[row0 + rl], s);
        }
    }
}

extern "C" void kernel_launch(void* const* d_in, const int* in_sizes, int n_in,
                              void* d_out, int out_size, void* d_ws, size_t ws_size,
                              hipStream_t stream) {
    const float* emb    = (const float*)d_in[0];
    const int*   labels = (const int*)d_in[1];
    const float* wgt    = (const float*)d_in[2];
    float* out = (float*)d_out;
    char* ws = (char*)d_ws;

    if (ws_size >= 103456768ull) {
        // ---- fast path: bf16 weight copy in workspace ----
        float* gacc          = (float*)(ws);                    // 4096
        float* target        = (float*)(ws + 4096);             // 4096
        unsigned short* ebf  = (unsigned short*)(ws + 8192);    // 1048576
        unsigned short* wbf  = (unsigned short*)(ws + 1056768); // 102400000

        prep_kernel<<<25513, 256, 0, stream>>>(wgt, wbf, emb, ebf, gacc);
        gemm_lse_kernel<<<(NCTP / 8) * 64, 256, 0, stream>>>(ebf, wbf, labels, gacc, target);
        finish_kernel<<<1, 1024, 0, stream>>>(gacc, target, out);
    } else {
        // ---- fallback: on-the-fly W conversion ----
        float* gacc          = (float*)(ws);                    // 4096
        float* target        = (float*)(ws + 4096);             // 4096
        unsigned short* ebf  = (unsigned short*)(ws + 8192);    // 1048576
        float* rnorm         = (float*)(ws + 1056768);          // 400000

        prep_fb_kernel<<<25513, 256, 0, stream>>>(wgt, rnorm, emb, ebf, gacc);
        dim3 gridB(B_N / BM, NCT);
        gemm_lse_fb_kernel<<<gridB, 256, 0, stream>>>(ebf, wgt, labels, rnorm, gacc, target);
        finish_kernel<<<1, 1024, 0, stream>>>(gacc, target, out);
    }
}

// Round 6
// 407.915 us; speedup vs baseline: 1.3142x; 1.1995x over previous
//
#include <hip/hip_runtime.h>
#include <math.h>

#define B_N 1024
#define D_K 512
#define C_N 100000
#define SCALEF 30.0f
#define COS_M 0.9553364891256061f
#define SIN_M 0.29552020666133955f
#define TH_C (-0.9553364891256061f)
#define MM_C 0.08865606199840186f
#define FIXM 160.0f

#define BM 128
#define BN 128
#define NCT ((C_N + BN - 1) / BN)   // 782
#define NCTP 784                    // padded to multiple of 8 for XCD swizzle

typedef short bf16x8 __attribute__((ext_vector_type(8)));
typedef float f32x4  __attribute__((ext_vector_type(4)));

__device__ inline unsigned bf16rne(float f) {
    unsigned u = __float_as_uint(f);
    u += 0x7fffu + ((u >> 16) & 1u);
    return u >> 16;
}
__device__ inline unsigned pk2(float lo, float hi) {
    return bf16rne(lo) | (bf16rne(hi) << 16);
}
// pack 4 floats -> 4 fp8 e4m3 bytes (HW RNE)
__device__ inline int pkf8(float a, float b, float c, float d) {
    int r = __builtin_amdgcn_cvt_pk_fp8_f32(a, b, 0, false);
    r = __builtin_amdgcn_cvt_pk_fp8_f32(c, d, r, true);
    return r;
}

__device__ static __forceinline__ void async16(const void* g, void* l) {
    __builtin_amdgcn_global_load_lds(
        (const __attribute__((address_space(1))) unsigned int*)g,
        (__attribute__((address_space(3))) unsigned int*)l, 16, 0, 0);
}

// ---------- kernel P: W->fp8(x16/||w||), E->fp8(x4), exact label logits, zero out ----------
// blocks [0,25000):      normalize+convert 4 W rows each (fp8, x16)
// blocks [25000,25128):  convert embeddings (fp8, x4)
// blocks [25128,25384):  exact fp32 label-column logits (4 rows each)
// block  25384:          zero out[0]
__global__ __launch_bounds__(256) void prep_kernel(
    const float* __restrict__ w, unsigned char* __restrict__ wq8,
    const float* __restrict__ e, unsigned char* __restrict__ eq8,
    const int* __restrict__ labels, float* __restrict__ texact,
    float* __restrict__ out)
{
    int bid = blockIdx.x;
    int wave = threadIdx.x >> 6;
    int lane = threadIdx.x & 63;
    if (bid < 25000) {
        int c = bid * 4 + wave;
        const float4* p = (const float4*)(w + (size_t)c * D_K);
        float4 a = p[lane];
        float4 b = p[lane + 64];
        float s = a.x*a.x + a.y*a.y + a.z*a.z + a.w*a.w
                + b.x*b.x + b.y*b.y + b.z*b.z + b.w*b.w;
        #pragma unroll
        for (int off = 32; off; off >>= 1) s += __shfl_xor(s, off, 64);
        float rn = 16.0f / sqrtf(s);   // x16 scale: keeps fp8 values normal
        int o0 = pkf8(a.x * rn, a.y * rn, a.z * rn, a.w * rn);
        int o1 = pkf8(b.x * rn, b.y * rn, b.z * rn, b.w * rn);
        int* q = (int*)(wq8 + (size_t)c * D_K);
        q[lane] = o0;
        q[lane + 64] = o1;
    } else if (bid < 25128) {
        int i = (bid - 25000) * 256 + threadIdx.x;   // 16 floats each
        const float4* p = ((const float4*)e) + i * 4;
        float4 v0 = p[0], v1 = p[1], v2 = p[2], v3 = p[3];
        int4 o;
        o.x = pkf8(v0.x * 4.f, v0.y * 4.f, v0.z * 4.f, v0.w * 4.f);
        o.y = pkf8(v1.x * 4.f, v1.y * 4.f, v1.z * 4.f, v1.w * 4.f);
        o.z = pkf8(v2.x * 4.f, v2.y * 4.f, v2.z * 4.f, v2.w * 4.f);
        o.w = pkf8(v3.x * 4.f, v3.y * 4.f, v3.z * 4.f, v3.w * 4.f);
        ((int4*)eq8)[i] = o;
    } else if (bid < 25384) {
        int b = (bid - 25128) * 4 + wave;
        int lab = labels[b];
        const float4* pe = (const float4*)(e + (size_t)b * D_K);
        const float4* pw = (const float4*)(w + (size_t)lab * D_K);
        float4 e0 = pe[lane], e1 = pe[lane + 64];
        float4 w0 = pw[lane], w1 = pw[lane + 64];
        float dot = e0.x*w0.x + e0.y*w0.y + e0.z*w0.z + e0.w*w0.w
                  + e1.x*w1.x + e1.y*w1.y + e1.z*w1.z + e1.w*w1.w;
        float nrm = w0.x*w0.x + w0.y*w0.y + w0.z*w0.z + w0.w*w0.w
                  + w1.x*w1.x + w1.y*w1.y + w1.z*w1.z + w1.w*w1.w;
        #pragma unroll
        for (int off = 32; off; off >>= 1) {
            dot += __shfl_xor(dot, off, 64);
            nrm += __shfl_xor(nrm, off, 64);
        }
        if (lane == 0) {
            float cosv = dot / sqrtf(nrm);
            float sine = sqrtf(fminf(fmaxf(1.0f - cosv * cosv, 0.0f), 1.0f));
            float phi = cosv * COS_M - sine * SIN_M;
            phi = (cosv > TH_C) ? phi : (cosv - MM_C);
            texact[b] = SCALEF * phi;
        }
    } else {
        if (threadIdx.x == 0) out[0] = 0.0f;
    }
}

// ------------- kernel B: fp8 MFMA GEMM, BK=128, swizzled LDS -------------
// LDS tile: 128 rows x 128 B; row r's global 16B-chunk g stored at slot (g+r)&7.
// Staging thread t: rows (t>>3)+32p, slot t&7 -> LDS offset t*16 (uniform+lane*16).
__global__ __launch_bounds__(256) void gemm_lse_kernel(
    const unsigned char* __restrict__ eq8, const unsigned char* __restrict__ wq8,
    const int* __restrict__ labels,
    float* __restrict__ partial, float* __restrict__ labraw)
{
    __shared__ unsigned char As[BM * 128];   // 16 KB
    __shared__ unsigned char Bs[BN * 128];   // 16 KB
    __shared__ int   labS[BM];
    __shared__ float sS[BM][2];

    // XCD swizzle: bid = 64g + 8r + j -> ct = 8g+j (same XCD covers all 8 r of a ct)
    const int bid = blockIdx.x;
    const int g8 = bid >> 6, r8 = (bid >> 3) & 7, j8 = bid & 7;
    const int ct = g8 * 8 + j8;     // 0..783 (782,783 dummy: contribute s=0)
    const int row0 = r8 * BM;
    const int col0 = ct * BN;
    const int t = threadIdx.x;
    const int lane = t & 63, wave = t >> 6;
    const int wx = wave & 1, wy = wave >> 1;
    const int lc = lane & 15, q = lane >> 4;

    if (t < BM) labS[t] = labels[row0 + t];
    __syncthreads();

    const int srow = t >> 3;          // 0..31
    const int sslot = t & 7;
    const int gch = (sslot - srow) & 7;   // global 16B chunk (constant across p)
    const unsigned char* aptr = eq8 + (size_t)(row0 + srow) * D_K + gch * 16;
    int bR[4];
    #pragma unroll
    for (int p = 0; p < 4; ++p) {
        int br = col0 + 32 * p + srow;
        bR[p] = (br < C_N) ? br : (C_N - 1);
    }
    const unsigned char* bptr[4] = {
        wq8 + (size_t)bR[0] * D_K + gch * 16, wq8 + (size_t)bR[1] * D_K + gch * 16,
        wq8 + (size_t)bR[2] * D_K + gch * 16, wq8 + (size_t)bR[3] * D_K + gch * 16 };
    unsigned char* ldsA = As + t * 16;    // + p*4096
    unsigned char* ldsB = Bs + t * 16;

    f32x4 acc[4][4] = {};

    for (int it = 0; it < 4; ++it) {      // K = 4 x 128
        const int k0 = it * 128;
        __syncthreads();   // previous iter's fragment reads complete
        #pragma unroll
        for (int p = 0; p < 4; ++p)
            async16(aptr + (size_t)32 * p * D_K + k0, ldsA + p * 4096);
        #pragma unroll
        for (int p = 0; p < 4; ++p)
            async16(bptr[p] + k0, ldsB + p * 4096);
        __syncthreads();   // vmcnt drained -> tiles ready

        #pragma unroll
        for (int kh = 0; kh < 4; ++kh) {   // k32 sub-steps
            long aF[4], bF[4];
            const int c16 = kh * 2 + (q >> 1);   // 16B chunk index of this frag
            const int h8 = (q & 1) * 8;
            #pragma unroll
            for (int si = 0; si < 4; ++si) {
                int r = wy * 64 + si * 16 + lc;
                int slot = (c16 + r) & 7;
                aF[si] = *(const long*)(As + r * 128 + slot * 16 + h8);
            }
            #pragma unroll
            for (int sj = 0; sj < 4; ++sj) {
                int r = wx * 64 + sj * 16 + lc;
                int slot = (c16 + r) & 7;
                bF[sj] = *(const long*)(Bs + r * 128 + slot * 16 + h8);
            }
            #pragma unroll
            for (int si = 0; si < 4; ++si)
                #pragma unroll
                for (int sj = 0; sj < 4; ++sj)
                    acc[si][sj] = __builtin_amdgcn_mfma_f32_16x16x32_fp8_fp8(
                        aF[si], bF[sj], acc[si][sj], 0, 0, 0);
        }
    }

    // ---- epilogue: plain logits (margin handled exactly in reduce), fixed-max exp-sum ----
    // C/D layout: col = lane&15, row = quad*4 + reg.  acc = 64 * cosine.
    const float LSC = SCALEF / 64.0f;
    #pragma unroll
    for (int si = 0; si < 4; ++si) {
        #pragma unroll
        for (int reg = 0; reg < 4; ++reg) {
            int rl = wy * 64 + si * 16 + q * 4 + reg;
            int lab = labS[rl];
            float s = 0.0f;
            #pragma unroll
            for (int sj = 0; sj < 4; ++sj) {
                int cg = col0 + wx * 64 + sj * 16 + lc;
                float lv = acc[si][sj][reg] * LSC;
                if (cg == lab) labraw[row0 + rl] = lv;
                if (cg < C_N) s += __expf(lv - FIXM);
            }
            #pragma unroll
            for (int off = 1; off < 16; off <<= 1)
                s += __shfl_xor(s, off, 64);
            if (lc == 0) sS[rl][wx] = s;
        }
    }
    __syncthreads();
    if (t < BM)
        partial[(size_t)ct * B_N + row0 + t] = sS[t][0] + sS[t][1];   // [ct][b]
}

// ------------- kernel R: per-row sum + label correction + mean (atomic) -------------
__global__ __launch_bounds__(256) void reduce_kernel(
    const float* __restrict__ partial, const float* __restrict__ labraw,
    const float* __restrict__ texact, float* __restrict__ out)
{
    int b = blockIdx.x;
    int t = threadIdx.x;
    float s = 0.0f;
    #pragma unroll
    for (int ct = t; ct < NCTP; ct += 256) s += partial[(size_t)ct * B_N + b];
    #pragma unroll
    for (int off = 1; off < 64; off <<= 1) s += __shfl_xor(s, off, 64);
    __shared__ float ss[4];
    int wave = t >> 6, lane = t & 63;
    if (lane == 0) ss[wave] = s;
    __syncthreads();
    if (t == 0) {
        float stot = ss[0] + ss[1] + ss[2] + ss[3];
        float te = texact[b];
        // swap fp8 label term for the exact margin-adjusted term
        stot += __expf(te - FIXM) - __expf(labraw[b] - FIXM);
        float nll = (FIXM + logf(stot)) - te;
        atomicAdd(out, nll * (1.0f / (float)B_N));
    }
}

// ===================== fallback path (small ws: bf16 on-the-fly) =====================
__global__ __launch_bounds__(256) void prep_fb_kernel(
    const float* __restrict__ w, float* __restrict__ rnorm,
    const float* __restrict__ e, unsigned short* __restrict__ ebf,
    float* __restrict__ gacc)
{
    int bid = blockIdx.x;
    if (bid < 25000) {
        int wave = threadIdx.x >> 6;
        int lane = threadIdx.x & 63;
        int c = bid * 4 + wave;
        const float4* p = (const float4*)(w + (size_t)c * D_K);
        float4 a = p[lane];
        float4 b = p[lane + 64];
        float s = a.x*a.x + a.y*a.y + a.z*a.z + a.w*a.w
                + b.x*b.x + b.y*b.y + b.z*b.z + b.w*b.w;
        #pragma unroll
        for (int off = 32; off; off >>= 1) s += __shfl_xor(s, off, 64);
        if (lane == 0) rnorm[c] = 1.0f / sqrtf(s);
    } else if (bid < 25512) {
        int i = (bid - 25000) * 256 + threadIdx.x;
        float4 v = ((const float4*)e)[i];
        uint2 o;
        o.x = pk2(v.x, v.y);
        o.y = pk2(v.z, v.w);
        ((uint2*)ebf)[i] = o;
    } else {
        float4 z = make_float4(0.f, 0.f, 0.f, 0.f);
        ((float4*)gacc)[threadIdx.x] = z;
    }
}

#define ROWS 40
__global__ __launch_bounds__(256) void gemm_lse_fb_kernel(
    const unsigned short* __restrict__ ebf, const float* __restrict__ wgt,
    const int* __restrict__ labels, const float* __restrict__ rnorm,
    float* __restrict__ gacc, float* __restrict__ target)
{
    __shared__ short As[BM * ROWS];
    __shared__ short Bs[BN * ROWS];
    __shared__ float rnS[BN];
    __shared__ int   labS[BM];

    const int rt = blockIdx.x;
    const int ct = blockIdx.y;
    const int row0 = rt * BM;
    const int col0 = ct * BN;
    const int t = threadIdx.x;
    const int lane = t & 63, wave = t >> 6;
    const int wx = wave & 1, wy = wave >> 1;
    const int lc = lane & 15, q = lane >> 4;

    if (t < BN) {
        int c = col0 + t;
        rnS[t] = (c < C_N) ? rnorm[c] : 0.0f;
    } else {
        labS[t - BN] = labels[row0 + (t - BN)];
    }
    __syncthreads();

    const int sr = t >> 1;
    const int sh = t & 1;
    const int cB = col0 + sr;
    const bool bval = cB < C_N;
    const float rn = rnS[sr];
    const unsigned short* aptr = ebf + (size_t)(row0 + sr) * D_K + sh * 16;
    const float* bptr0 = wgt + (size_t)(bval ? cB : 0) * D_K + sh * 16;

    f32x4 acc[4][4] = {};

    for (int it = 0; it < D_K / 32; ++it) {
        const int k0 = it * 32;
        uint4 a0 = ((const uint4*)(aptr + k0))[0];
        uint4 a1 = ((const uint4*)(aptr + k0))[1];
        float4 b0 = make_float4(0.f,0.f,0.f,0.f), b1 = b0, b2 = b0, b3 = b0;
        if (bval) {
            const float4* bp = (const float4*)(bptr0 + k0);
            b0 = bp[0]; b1 = bp[1]; b2 = bp[2]; b3 = bp[3];
        }
        uint4 w0, w1;
        w0.x = pk2(b0.x * rn, b0.y * rn); w0.y = pk2(b0.z * rn, b0.w * rn);
        w0.z = pk2(b1.x * rn, b1.y * rn); w0.w = pk2(b1.z * rn, b1.w * rn);
        w1.x = pk2(b2.x * rn, b2.y * rn); w1.y = pk2(b2.z * rn, b2.w * rn);
        w1.z = pk2(b3.x * rn, b3.y * rn); w1.w = pk2(b3.z * rn, b3.w * rn);

        __syncthreads();
        *(uint4*)(As + sr * ROWS + sh * 16)     = a0;
        *(uint4*)(As + sr * ROWS + sh * 16 + 8) = a1;
        *(uint4*)(Bs + sr * ROWS + sh * 16)     = w0;
        *(uint4*)(Bs + sr * ROWS + sh * 16 + 8) = w1;
        __syncthreads();

        bf16x8 aF[4], bF[4];
        #pragma unroll
        for (int si = 0; si < 4; ++si)
            aF[si] = *(const bf16x8*)(As + (wy * 64 + si * 16 + lc) * ROWS + q * 8);
        #pragma unroll
        for (int sj = 0; sj < 4; ++sj)
            bF[sj] = *(const bf16x8*)(Bs + (wx * 64 + sj * 16 + lc) * ROWS + q * 8);
        #pragma unroll
        for (int si = 0; si < 4; ++si)
            #pragma unroll
            for (int sj = 0; sj < 4; ++sj)
                acc[si][sj] = __builtin_amdgcn_mfma_f32_16x16x32_bf16(
                    aF[si], bF[sj], acc[si][sj], 0, 0, 0);
    }

    #pragma unroll
    for (int si = 0; si < 4; ++si) {
        #pragma unroll
        for (int reg = 0; reg < 4; ++reg) {
            int rl = wy * 64 + si * 16 + q * 4 + reg;
            int lab = labS[rl];
            float s = 0.0f;
            #pragma unroll
            for (int sj = 0; sj < 4; ++sj) {
                int cg = col0 + wx * 64 + sj * 16 + lc;
                float cosv = acc[si][sj][reg];
                float v;
                if (cg == lab) {
                    float sine = sqrtf(fminf(fmaxf(1.0f - cosv * cosv, 0.0f), 1.0f));
                    float phi = cosv * COS_M - sine * SIN_M;
                    phi = (cosv > TH_C) ? phi : (cosv - MM_C);
                    v = SCALEF * phi;
                    target[row0 + rl] = v;
                } else {
                    v = SCALEF * cosv;
                }
                if (cg < C_N) s += __expf(v - FIXM);
            }
            #pragma unroll
            for (int off = 1; off < 16; off <<= 1)
                s += __shfl_xor(s, off, 64);
            if (lc == 0) atomicAdd(&gacc[row0 + rl], s);
        }
    }
}

__global__ __launch_bounds__(1024) void finish_fb_kernel(
    const float* __restrict__ gacc, const float* __restrict__ target,
    float* __restrict__ out)
{
    int t = threadIdx.x;
    float v = (FIXM + logf(gacc[t])) - target[t];
    #pragma unroll
    for (int off = 1; off < 64; off <<= 1) v += __shfl_xor(v, off, 64);
    __shared__ float ws[16];
    int wave = t >> 6, lane = t & 63;
    if (lane == 0) ws[wave] = v;
    __syncthreads();
    if (t == 0) {
        float sum = 0.f;
        for (int w = 0; w < 16; ++w) sum += ws[w];
        out[0] = sum / (float)B_N;
    }
}

extern "C" void kernel_launch(void* const* d_in, const int* in_sizes, int n_in,
                              void* d_out, int out_size, void* d_ws, size_t ws_size,
                              hipStream_t stream) {
    const float* emb    = (const float*)d_in[0];
    const int*   labels = (const int*)d_in[1];
    const float* wgt    = (const float*)d_in[2];
    float* out = (float*)d_out;
    char* ws = (char*)d_ws;

    if (ws_size >= 56000000ull) {
        // ---- fast path: fp8 weight/emb copies in workspace ----
        float* texact        = (float*)(ws);                    // 4096
        float* labraw        = (float*)(ws + 4096);             // 4096
        float* partial       = (float*)(ws + 8192);             // 784*1024*4 = 3211264
        unsigned char* eq8   = (unsigned char*)(ws + 3219456);  // 524288
        unsigned char* wq8   = (unsigned char*)(ws + 3743744);  // 51200000

        prep_kernel<<<25385, 256, 0, stream>>>(wgt, wq8, emb, eq8, labels, texact, out);
        gemm_lse_kernel<<<(NCTP / 8) * 64, 256, 0, stream>>>(eq8, wq8, labels, partial, labraw);
        reduce_kernel<<<B_N, 256, 0, stream>>>(partial, labraw, texact, out);
    } else {
        // ---- fallback: bf16 on-the-fly conversion ----
        float* gacc          = (float*)(ws);                    // 4096
        float* target        = (float*)(ws + 4096);             // 4096
        unsigned short* ebf  = (unsigned short*)(ws + 8192);    // 1048576
        float* rnorm         = (float*)(ws + 1056768);          // 400000

        prep_fb_kernel<<<25513, 256, 0, stream>>>(wgt, rnorm, emb, ebf, gacc);
        dim3 gridB(B_N / BM, NCT);
        gemm_lse_fb_kernel<<<gridB, 256, 0, stream>>>(ebf, wgt, labels, rnorm, gacc, target);
        finish_fb_kernel<<<1, 1024, 0, stream>>>(gacc, target, out);
    }
}